// Round 1
// 570.550 us; speedup vs baseline: 1.2245x; 1.2245x over previous
//
#include <hip/hip_runtime.h>
#include <cstdint>
#include <cstddef>

// Problem constants (reference: N=16384, DX1=DX2=1024, DH=2048)
#define NR 16384
#define DX 1024
#define DH 2048

typedef unsigned short u16;
typedef _Float16 half8 __attribute__((ext_vector_type(8)));
typedef _Float16 half4v __attribute__((ext_vector_type(4)));
typedef float f32x4 __attribute__((ext_vector_type(4)));

__device__ __forceinline__ u16 f2h_bits(float v) {
    union { _Float16 h; u16 u; } c;
    c.h = (_Float16)v;
    return c.u;
}

// async global->LDS, 16B per lane; LDS dest = wave-uniform base + lane*16
__device__ __forceinline__ void gl_lds16(const void* g, void* l) {
    __builtin_amdgcn_global_load_lds(
        (const __attribute__((address_space(1))) void*)g,
        (__attribute__((address_space(3))) void*)l, 16, 0, 0);
}

// ---------------------------------------------------------------------------
// fp32 -> fp16 elementwise cast (vectorized float4 -> half4). n must be %1024.
__global__ __launch_bounds__(256) void cast_f32_f16(const float* __restrict__ in,
                                                    u16* __restrict__ out) {
    size_t i = ((size_t)blockIdx.x * 256 + threadIdx.x) * 4;
    float4 v = *(const float4*)&in[i];
    half4v o = { (_Float16)v.x, (_Float16)v.y, (_Float16)v.z, (_Float16)v.w };
    *(half4v*)&out[i] = o;
}

// ---------------------------------------------------------------------------
// W [K,D] fp32 -> Wt [D,K] fp16 (LDS tiled transpose). K,D % 32 == 0.
__global__ __launch_bounds__(256) void transpose_cast(const float* __restrict__ in,
                                                      u16* __restrict__ out,
                                                      int K, int D) {
    __shared__ float tile[32][33];
    int tx = threadIdx.x & 31;
    int ty = threadIdx.x >> 5;                  // 0..7
    int d0 = blockIdx.x * 32, k0 = blockIdx.y * 32;
#pragma unroll
    for (int i = 0; i < 32; i += 8)
        tile[ty + i][tx] = in[(size_t)(k0 + ty + i) * D + d0 + tx];
    __syncthreads();
#pragma unroll
    for (int i = 0; i < 32; i += 8)
        out[(size_t)(d0 + ty + i) * K + k0 + tx] = f2h_bits(tile[tx][ty + i]);
}

// ---------------------------------------------------------------------------
// 256x256-tile 8-phase GEMM (m201 template, plain HIP), BK=64, 512 threads =
// 8 waves (2M x 4N), 16x16x32 f16 MFMA. A [M,K] f16 rm, Bt [N,K] f16 rm.
// LDS: As/Bs double-buffered [2][256][64] halfs = 128 KiB total -> 1 block/CU.
//
// Swizzle (T2, st_16x32): involution swz(x) = x ^ (((x>>9)&1)<<5) on the
// full-tile BYTE offset. Staged via pre-swizzled GLOBAL source (LDS dest of
// global_load_lds must stay linear), read via swizzled ds_read address.
// For reads the XOR bit reduces to a per-lane constant ((fr>>2)&1).
//
// Phase schedule per K-tile t (buffer bb = t&1), derived WAR/RAW-safe:
//   p0: read a[0..3]         | stage Ahi(t+1) | MFMA m0-3 x n0-1
//       read b[0..1]
//   p1: read b[2..3]         | stage Bhi(t+1) | MFMA m0-3 x n2-3
//   p2: re-read a[. +64rows] | stage Blo(t+2) | MFMA m4-7 x n0-1
//   p3: (no reads)           | stage Alo(t+2) | MFMA m4-7 x n2-3, vmcnt(4|0)
// Each phase: [ds_reads][stage] s_barrier; lgkmcnt(0); setprio(1) MFMA
// setprio(0); [p3: counted vmcnt] s_barrier.  vmcnt(4) = the 2 stages of
// p2+p3 (tile t+2) may stay in flight; everything older (all of tile t+1)
// drains. Tail uses vmcnt(0) since the newest loads are then needed.
//
// MODE 0: C[M,N] = A@B + bias (f16 out)
// MODE 1: Lacc[row] += sum_col (A@B + bias - Xref)^2 (atomic per row)
template <int MODE>
__global__ __launch_bounds__(512, 2) void gemm256(
    const u16* __restrict__ A, const u16* __restrict__ Bt,
    const float* __restrict__ bias,
    u16* __restrict__ C, const float* __restrict__ Xref,
    float* __restrict__ Lacc,
    int M, int N, int K) {
    __shared__ __align__(16) u16 As[2][16384];
    __shared__ __align__(16) u16 Bs[2][16384];

    // bijective XCD-aware block swizzle (nwg % 8 == 0 for all our shapes)
    const int nwg = gridDim.x;
    const int bid = blockIdx.x;
    const int cpx = nwg >> 3;
    const int wg  = (bid & 7) * cpx + (bid >> 3);
    const int NBN = N >> 8;
    const int m0 = (wg / NBN) * 256;
    const int n0 = (wg % NBN) * 256;

    const int tid  = threadIdx.x;
    const int lane = tid & 63;
    const int w    = tid >> 6;          // 0..7
    const int wr   = w >> 2;            // 0..1 (rows, 128 each)
    const int wn   = w & 3;             // 0..3 (cols, 64 each)
    const int fr   = lane & 15;
    const int qa   = (lane >> 4) * 8;   // k-offset (halfs) of lane's fragment
    const int NT   = K >> 6;            // K-tiles (>= 16 for our shapes)

    f32x4 acc[8][4] = {};

    // swizzled ds_read base offsets (u16 units); frag (m,ks) = base + m*1024
    // + ks*32 (offsets only touch bits >= 5 of byte addr -> XOR commutes)
    const int sxh   = ((fr >> 2) & 1) << 4;
    const int aoff0 = (((wr * 128 + fr) * 64) + qa) ^ sxh;
    const int boff0 = (((wn * 64 + fr) * 64) + qa) ^ sxh;

    // staging: one 128x64-half half-tile (16 KB) per call, two 8 KB sweeps.
    // source chunk pre-swizzled: c = (tid&7) ^ ((tid>>5)&1)<<1
    const int stg_c = (((tid & 7) ^ (((tid >> 5) & 1) << 1))) << 3;  // halfs
    const int stg_r = tid >> 3;                                      // 0..63
    const int stg_w = (tid >> 6) << 9;  // wave-uniform LDS offset (halfs)

#define STAGE(G, ldK, rowbase, kt, lbase, half_idx)                            \
    do {                                                                       \
        const u16* _s = (G) + (size_t)((rowbase) + (half_idx) * 128 + stg_r) * \
                                  (ldK) + (kt) * 64 + stg_c;                   \
        u16* _d = (lbase) + (half_idx) * 8192 + stg_w;                         \
        gl_lds16(_s, _d);                                                      \
        gl_lds16(_s + (size_t)64 * (ldK), _d + 4096);                          \
    } while (0)

#define MFMA_(d, av, bv) \
    d = __builtin_amdgcn_mfma_f32_16x16x32_f16(av, bv, d, 0, 0, 0)

    // ---- prologue: tile0 (all 4 halves), then Blo(1), Alo(1) ----
    STAGE(A, K, m0, 0, &As[0][0], 0);
    STAGE(Bt, K, n0, 0, &Bs[0][0], 0);
    STAGE(A, K, m0, 0, &As[0][0], 1);
    STAGE(Bt, K, n0, 0, &Bs[0][0], 1);
    STAGE(Bt, K, n0, 1, &Bs[1][0], 0);
    STAGE(A, K, m0, 1, &As[1][0], 0);
    asm volatile("s_waitcnt vmcnt(4)" ::: "memory");  // tile0 landed
    __builtin_amdgcn_s_barrier();

    for (int t = 0; t < NT; ++t) {
        const int bb = t & 1;
        const u16* Ab = &As[bb][0];
        const u16* Bb = &Bs[bb][0];
        u16* Acur = &As[bb][0];
        u16* Bcur = &Bs[bb][0];
        u16* Anx  = &As[bb ^ 1][0];
        u16* Bnx  = &Bs[bb ^ 1][0];
        half8 af[4][2], bf[4][2];

        // ---------------- phase 0 ----------------
#pragma unroll
        for (int m = 0; m < 4; ++m)
#pragma unroll
            for (int ks = 0; ks < 2; ++ks)
                af[m][ks] = *(const half8*)&Ab[aoff0 + m * 1024 + ks * 32];
#pragma unroll
        for (int n = 0; n < 2; ++n)
#pragma unroll
            for (int ks = 0; ks < 2; ++ks)
                bf[n][ks] = *(const half8*)&Bb[boff0 + n * 1024 + ks * 32];
        if (t + 1 < NT) STAGE(A, K, m0, t + 1, Anx, 1);
        __builtin_amdgcn_s_barrier();
        asm volatile("s_waitcnt lgkmcnt(0)" ::: "memory");
        __builtin_amdgcn_s_setprio(1);
#pragma unroll
        for (int m = 0; m < 4; ++m)
#pragma unroll
            for (int n = 0; n < 2; ++n)
#pragma unroll
                for (int ks = 0; ks < 2; ++ks)
                    MFMA_(acc[m][n], af[m][ks], bf[n][ks]);
        __builtin_amdgcn_s_setprio(0);
        __builtin_amdgcn_s_barrier();

        // ---------------- phase 1 ----------------
#pragma unroll
        for (int n = 2; n < 4; ++n)
#pragma unroll
            for (int ks = 0; ks < 2; ++ks)
                bf[n][ks] = *(const half8*)&Bb[boff0 + n * 1024 + ks * 32];
        if (t + 1 < NT) STAGE(Bt, K, n0, t + 1, Bnx, 1);
        __builtin_amdgcn_s_barrier();
        asm volatile("s_waitcnt lgkmcnt(0)" ::: "memory");
        __builtin_amdgcn_s_setprio(1);
#pragma unroll
        for (int m = 0; m < 4; ++m)
#pragma unroll
            for (int n = 2; n < 4; ++n)
#pragma unroll
                for (int ks = 0; ks < 2; ++ks)
                    MFMA_(acc[m][n], af[m][ks], bf[n][ks]);
        __builtin_amdgcn_s_setprio(0);
        __builtin_amdgcn_s_barrier();

        // ---------------- phase 2 ----------------
#pragma unroll
        for (int m = 0; m < 4; ++m)
#pragma unroll
            for (int ks = 0; ks < 2; ++ks)
                af[m][ks] = *(const half8*)&Ab[aoff0 + 4096 + m * 1024 + ks * 32];
        if (t + 2 < NT) STAGE(Bt, K, n0, t + 2, Bcur, 0);
        __builtin_amdgcn_s_barrier();
        asm volatile("s_waitcnt lgkmcnt(0)" ::: "memory");
        __builtin_amdgcn_s_setprio(1);
#pragma unroll
        for (int m = 0; m < 4; ++m)
#pragma unroll
            for (int n = 0; n < 2; ++n)
#pragma unroll
                for (int ks = 0; ks < 2; ++ks)
                    MFMA_(acc[4 + m][n], af[m][ks], bf[n][ks]);
        __builtin_amdgcn_s_setprio(0);
        __builtin_amdgcn_s_barrier();

        // ---------------- phase 3 ----------------
        if (t + 2 < NT) STAGE(A, K, m0, t + 2, Acur, 0);
        __builtin_amdgcn_s_barrier();
        __builtin_amdgcn_s_setprio(1);
#pragma unroll
        for (int m = 0; m < 4; ++m)
#pragma unroll
            for (int n = 2; n < 4; ++n)
#pragma unroll
                for (int ks = 0; ks < 2; ++ks)
                    MFMA_(acc[4 + m][n], af[m][ks], bf[n][ks]);
        __builtin_amdgcn_s_setprio(0);
        if (t + 2 < NT)
            asm volatile("s_waitcnt vmcnt(4)" ::: "memory");
        else
            asm volatile("s_waitcnt vmcnt(0)" ::: "memory");
        __builtin_amdgcn_s_barrier();
    }

    // epilogue: C/D layout col = lane&15, row = (lane>>4)*4 + reg  [m89/m91]
    const int colbase = n0 + wn * 64 + fr;
    float bj[4];
#pragma unroll
    for (int j = 0; j < 4; ++j) bj[j] = bias[colbase + j * 16];

    if (MODE == 0) {
#pragma unroll
        for (int i = 0; i < 8; ++i) {
            int rowb = m0 + wr * 128 + i * 16 + (lane >> 4) * 4;
#pragma unroll
            for (int r = 0; r < 4; ++r) {
                size_t ro = (size_t)(rowb + r) * N;
#pragma unroll
                for (int j = 0; j < 4; ++j)
                    C[ro + colbase + j * 16] = f2h_bits(acc[i][j][r] + bj[j]);
            }
        }
    } else {
#pragma unroll
        for (int i = 0; i < 8; ++i) {
            int rowb = m0 + wr * 128 + i * 16 + (lane >> 4) * 4;
#pragma unroll
            for (int r = 0; r < 4; ++r) {
                size_t ro = (size_t)(rowb + r) * N;
                float s = 0.f;
#pragma unroll
                for (int j = 0; j < 4; ++j) {
                    float d = acc[i][j][r] + bj[j] - Xref[ro + colbase + j * 16];
                    s += d * d;
                }
                // reduce over the 16 lanes sharing this row (cols)
                s += __shfl_xor(s, 1, 64);
                s += __shfl_xor(s, 2, 64);
                s += __shfl_xor(s, 4, 64);
                s += __shfl_xor(s, 8, 64);
                if (fr == 0) atomicAdd(&Lacc[rowb + r], s);
            }
        }
    }
#undef STAGE
#undef MFMA_
}

// ---------------------------------------------------------------------------
// Per-row L3 = sum (h1-h2)^2 and L4row = sum (h1+h2)*whoW. One block per row.
__global__ __launch_bounds__(256) void l34_kernel(
    const u16* __restrict__ H1, const u16* __restrict__ H2,
    const float* __restrict__ whoW,
    float* __restrict__ L3, float* __restrict__ L4) {
    int row = blockIdx.x;
    int tid = threadIdx.x;
    const half8 h1 = *(const half8*)&H1[(size_t)row * DH + tid * 8];
    const half8 h2 = *(const half8*)&H2[(size_t)row * DH + tid * 8];
    float4 w0 = *(const float4*)&whoW[tid * 8];
    float4 w1 = *(const float4*)&whoW[tid * 8 + 4];
    float wv[8] = { w0.x, w0.y, w0.z, w0.w, w1.x, w1.y, w1.z, w1.w };
    float s3 = 0.f, s4 = 0.f;
#pragma unroll
    for (int u = 0; u < 8; ++u) {
        float a = (float)h1[u], b = (float)h2[u];
        float d = a - b;
        s3 += d * d;
        s4 += (a + b) * wv[u];
    }
#pragma unroll
    for (int off = 1; off < 64; off <<= 1) {
        s3 += __shfl_xor(s3, off, 64);
        s4 += __shfl_xor(s4, off, 64);
    }
    __shared__ float sm[8];
    int wvi = tid >> 6, ln = tid & 63;
    if (ln == 0) { sm[wvi] = s3; sm[4 + wvi] = s4; }
    __syncthreads();
    if (tid == 0) {
        L3[row] = sm[0] + sm[1] + sm[2] + sm[3];
        L4[row] = sm[4] + sm[5] + sm[6] + sm[7];
    }
}

// ---------------------------------------------------------------------------
// loss = sum_r L1^2 + L2^2 + L3^2 + (0.5*(L4row + who_b) - Y)^2
__global__ __launch_bounds__(1024) void final_reduce(
    const float* __restrict__ L1, const float* __restrict__ L2,
    const float* __restrict__ L3, const float* __restrict__ L4,
    const float* __restrict__ Y, const float* __restrict__ whob,
    float* __restrict__ out) {
    float s = 0.f;
    float wb = whob[0];
    for (int r = threadIdx.x; r < NR; r += 1024) {
        float l4 = 0.5f * (L4[r] + wb) - Y[r];
        s += L1[r] * L1[r] + L2[r] * L2[r] + L3[r] * L3[r] + l4 * l4;
    }
#pragma unroll
    for (int off = 1; off < 64; off <<= 1) s += __shfl_xor(s, off, 64);
    __shared__ float sm[16];
    int w = threadIdx.x >> 6, ln = threadIdx.x & 63;
    if (ln == 0) sm[w] = s;
    __syncthreads();
    if (threadIdx.x == 0) {
        float t = 0.f;
#pragma unroll
        for (int i = 0; i < 16; ++i) t += sm[i];
        out[0] = t;
    }
}

// ---------------------------------------------------------------------------
extern "C" void kernel_launch(void* const* d_in, const int* in_sizes, int n_in,
                              void* d_out, int out_size, void* d_ws, size_t ws_size,
                              hipStream_t stream) {
    const float* X1   = (const float*)d_in[0];
    const float* X2   = (const float*)d_in[1];
    const float* Y    = (const float*)d_in[2];
    const float* w1hW = (const float*)d_in[3];
    const float* w1hb = (const float*)d_in[4];
    const float* w2hW = (const float*)d_in[5];
    const float* w2hb = (const float*)d_in[6];
    const float* wh1W = (const float*)d_in[7];
    const float* wh1b = (const float*)d_in[8];
    const float* wh2W = (const float*)d_in[9];
    const float* wh2b = (const float*)d_in[10];
    const float* whoW = (const float*)d_in[11];
    const float* whob = (const float*)d_in[12];

    // workspace layout (~208.3 MB total)
    char* ws = (char*)d_ws;
    u16* X1h  = (u16*)(ws);                               // 16384x1024 fp16
    u16* X2h  = X1h + (size_t)NR * DX;
    u16* H1h  = X2h + (size_t)NR * DX;                    // 16384x2048 fp16
    u16* H2h  = H1h + (size_t)NR * DH;
    u16* w1hT = H2h + (size_t)NR * DH;                    // [DH][DX]
    u16* w2hT = w1hT + (size_t)DH * DX;
    u16* wh1T = w2hT + (size_t)DH * DX;                   // [DX][DH]
    u16* wh2T = wh1T + (size_t)DX * DH;
    float* L1a = (float*)(wh2T + (size_t)DX * DH);        // 4 x 16384 f32
    float* L2a = L1a + NR;
    float* L3a = L2a + NR;
    float* L4a = L3a + NR;

    // zero the atomically-accumulated arrays (ws is poisoned 0xAA each call)
    hipMemsetAsync(L1a, 0, 2 * (size_t)NR * sizeof(float), stream);

    // casts
    cast_f32_f16<<<NR * DX / 1024, 256, 0, stream>>>(X1, X1h);
    cast_f32_f16<<<NR * DX / 1024, 256, 0, stream>>>(X2, X2h);
    transpose_cast<<<dim3(DH / 32, DX / 32), 256, 0, stream>>>(w1hW, w1hT, DX, DH);
    transpose_cast<<<dim3(DH / 32, DX / 32), 256, 0, stream>>>(w2hW, w2hT, DX, DH);
    transpose_cast<<<dim3(DX / 32, DH / 32), 256, 0, stream>>>(wh1W, wh1T, DH, DX);
    transpose_cast<<<dim3(DX / 32, DH / 32), 256, 0, stream>>>(wh2W, wh2T, DH, DX);

    // H1 = X1@w1h + b, H2 = X2@w2h + b  (fp16 out)
    gemm256<0><<<dim3((NR / 256) * (DH / 256)), 512, 0, stream>>>(
        X1h, w1hT, w1hb, H1h, nullptr, nullptr, NR, DH, DX);
    gemm256<0><<<dim3((NR / 256) * (DH / 256)), 512, 0, stream>>>(
        X2h, w2hT, w2hb, H2h, nullptr, nullptr, NR, DH, DX);

    // L3, L4row from H1, H2
    l34_kernel<<<NR, 256, 0, stream>>>(H1h, H2h, whoW, L3a, L4a);

    // L1 = rowsq(H1@wh2 + b - X2), L2 = rowsq(H2@wh1 + b - X1)
    gemm256<1><<<dim3((NR / 256) * (DX / 256)), 512, 0, stream>>>(
        H1h, wh2T, wh2b, nullptr, X2, L1a, NR, DX, DH);
    gemm256<1><<<dim3((NR / 256) * (DX / 256)), 512, 0, stream>>>(
        H2h, wh1T, wh1b, nullptr, X1, L2a, NR, DX, DH);

    final_reduce<<<1, 1024, 0, stream>>>(L1a, L2a, L3a, L4a, Y, whob, (float*)d_out);
}

// Round 2
// 558.898 us; speedup vs baseline: 1.2501x; 1.0208x over previous
//
#include <hip/hip_runtime.h>
#include <cstdint>
#include <cstddef>

// Problem constants (reference: N=16384, DX1=DX2=1024, DH=2048)
#define NR 16384
#define DX 1024
#define DH 2048

typedef unsigned short u16;
typedef _Float16 half8 __attribute__((ext_vector_type(8)));
typedef _Float16 half4v __attribute__((ext_vector_type(4)));
typedef float f32x4 __attribute__((ext_vector_type(4)));

__device__ __forceinline__ u16 f2h_bits(float v) {
    union { _Float16 h; u16 u; } c;
    c.h = (_Float16)v;
    return c.u;
}

__device__ __forceinline__ float h2f_bits(u16 v) {
    union { u16 u; _Float16 h; } c;
    c.u = v;
    return (float)c.h;
}

// async global->LDS, 16B per lane; LDS dest = wave-uniform base + lane*16
__device__ __forceinline__ void gl_lds16(const void* g, void* l) {
    __builtin_amdgcn_global_load_lds(
        (const __attribute__((address_space(1))) void*)g,
        (__attribute__((address_space(3))) void*)l, 16, 0, 0);
}

// ---------------------------------------------------------------------------
// fp32 -> fp16 elementwise cast (vectorized float4 -> half4). n must be %1024.
__global__ __launch_bounds__(256) void cast_f32_f16(const float* __restrict__ in,
                                                    u16* __restrict__ out) {
    size_t i = ((size_t)blockIdx.x * 256 + threadIdx.x) * 4;
    float4 v = *(const float4*)&in[i];
    half4v o = { (_Float16)v.x, (_Float16)v.y, (_Float16)v.z, (_Float16)v.w };
    *(half4v*)&out[i] = o;
}

// ---------------------------------------------------------------------------
// W [K,D] fp32 -> Wt [D,K] fp16 (LDS tiled transpose). K,D % 32 == 0.
__global__ __launch_bounds__(256) void transpose_cast(const float* __restrict__ in,
                                                      u16* __restrict__ out,
                                                      int K, int D) {
    __shared__ float tile[32][33];
    int tx = threadIdx.x & 31;
    int ty = threadIdx.x >> 5;                  // 0..7
    int d0 = blockIdx.x * 32, k0 = blockIdx.y * 32;
#pragma unroll
    for (int i = 0; i < 32; i += 8)
        tile[ty + i][tx] = in[(size_t)(k0 + ty + i) * D + d0 + tx];
    __syncthreads();
#pragma unroll
    for (int i = 0; i < 32; i += 8)
        out[(size_t)(d0 + ty + i) * K + k0 + tx] = f2h_bits(tile[tx][ty + i]);
}

// ---------------------------------------------------------------------------
// 256x256-tile 8-phase GEMM (m201 template, plain HIP), BK=64, 512 threads =
// 8 waves (2M x 4N), 16x16x32 f16 MFMA. A [M,K] f16 rm, Bt [N,K] f16 rm.
// LDS: As/Bs double-buffered [2][256][64] halfs = 128 KiB total -> 1 block/CU.
//
// Swizzle (T2, full 3-bit, derived for 128B rows + ds_read_b128):
//   LDS chunk (16B) at (row, c) holds global chunk (row, c ^ (row&7)).
//   Staged via pre-swizzled GLOBAL source chunk (LDS dest of global_load_lds
//   must stay linear, rule #21); ds_read XORs its half-offset with
//   ((fr&7)<<3) — valid since every read row satisfies row&7 == fr&7
//   (all row offsets m*16, wr*128, +64 are multiples of 8).
//   Result: each wave64 b128 read covers all 8 bank-slots uniformly
//   (8 lanes/slot = structural minimum) vs 16-way conflict unswizzled.
//
// Phase schedule per K-tile t (buffer bb = t&1), WAR/RAW-safe:
//   p0: read a[0..3],b[0..1] | stage Ahi(t+1) | MFMA m0-3 x n0-1
//   p1: read b[2..3]         | stage Bhi(t+1) | MFMA m0-3 x n2-3
//   p2: read a[4..7]         | stage Blo(t+2) | MFMA m4-7 x n0-1
//   p3: (no reads)           | stage Alo(t+2) | MFMA m4-7 x n2-3, vmcnt(4|0)
// Each phase: [ds_reads][stage] s_barrier; lgkmcnt(0); setprio(1) MFMA
// setprio(0); [p3: counted vmcnt] s_barrier.  vmcnt(4) = the 2 stages of
// p2+p3 (tile t+2) stay in flight; everything older (tile t+1) drains.
//
// MODE 0: C = A@B + bias (f16 out)
// MODE 1: Lacc[row] += sum_col (A@B + bias - Xref)^2          (atomic)
// MODE 2: C = A@B + bias (f16 out)  AND per-row L3/L4 partials vs Hoth:
//         Lacc[row] += sum_col (hoth - c)^2
//         L4o[row]  += sum_col (hoth + c) * Wo[col]           (atomic)
template <int MODE>
__global__ __launch_bounds__(512, 2) void gemm256(
    const u16* __restrict__ A, const u16* __restrict__ Bt,
    const float* __restrict__ bias,
    u16* __restrict__ C, const float* __restrict__ Xref,
    float* __restrict__ Lacc,
    const u16* __restrict__ Hoth, const float* __restrict__ Wo,
    float* __restrict__ L4o,
    int M, int N, int K) {
    __shared__ __align__(16) u16 As[2][16384];
    __shared__ __align__(16) u16 Bs[2][16384];

    // bijective XCD-aware block swizzle (nwg % 8 == 0 for all our shapes)
    const int nwg = gridDim.x;
    const int bid = blockIdx.x;
    const int cpx = nwg >> 3;
    const int wg  = (bid & 7) * cpx + (bid >> 3);
    const int NBN = N >> 8;
    const int m0 = (wg / NBN) * 256;
    const int n0 = (wg % NBN) * 256;

    const int tid  = threadIdx.x;
    const int lane = tid & 63;
    const int w    = tid >> 6;          // 0..7
    const int wr   = w >> 2;            // 0..1 (rows, 128 each)
    const int wn   = w & 3;             // 0..3 (cols, 64 each)
    const int fr   = lane & 15;
    const int qa   = (lane >> 4) * 8;   // k-offset (halfs) of lane's fragment
    const int NT   = K >> 6;            // K-tiles (>= 16 for our shapes)

    f32x4 acc[8][4] = {};

    // swizzled ds_read bases per ks (u16 units). XOR bits are half-bits 3..5;
    // qa (bits 3-4) + ks*32 (bit 5) are folded BEFORE the XOR so no carries;
    // later adds (m*1024 = 16 rows, 4096 = 64 rows) only touch bits >= 10/12.
    const int sx = (fr & 7) << 3;
    int aofK[2], bofK[2];
#pragma unroll
    for (int ks = 0; ks < 2; ++ks) {
        aofK[ks] = (((wr * 128 + fr) * 64) + qa + ks * 32) ^ sx;
        bofK[ks] = (((wn * 64 + fr) * 64) + qa + ks * 32) ^ sx;
    }

    // staging: one 128x64-half half-tile (16 KB) per call, two 8 KB sweeps.
    // source chunk pre-swizzled: cc_src = cc ^ (row & 7), row = tid>>3
    // (second sweep row+64 has same &7). LDS dest stays linear.
    const int stg_c = ((tid & 7) ^ ((tid >> 3) & 7)) << 3;           // halfs
    const int stg_r = tid >> 3;                                      // 0..63
    const int stg_w = (tid >> 6) << 9;  // wave-uniform LDS offset (halfs)

#define STAGE(G, ldK, rowbase, kt, lbase, half_idx)                            \
    do {                                                                       \
        const u16* _s = (G) + (size_t)((rowbase) + (half_idx) * 128 + stg_r) * \
                                  (ldK) + (kt) * 64 + stg_c;                   \
        u16* _d = (lbase) + (half_idx) * 8192 + stg_w;                         \
        gl_lds16(_s, _d);                                                      \
        gl_lds16(_s + (size_t)64 * (ldK), _d + 4096);                          \
    } while (0)

#define MFMA_(d, av, bv) \
    d = __builtin_amdgcn_mfma_f32_16x16x32_f16(av, bv, d, 0, 0, 0)

    // ---- prologue: tile0 (all 4 halves), then Blo(1), Alo(1) ----
    STAGE(A, K, m0, 0, &As[0][0], 0);
    STAGE(Bt, K, n0, 0, &Bs[0][0], 0);
    STAGE(A, K, m0, 0, &As[0][0], 1);
    STAGE(Bt, K, n0, 0, &Bs[0][0], 1);
    STAGE(Bt, K, n0, 1, &Bs[1][0], 0);
    STAGE(A, K, m0, 1, &As[1][0], 0);
    asm volatile("s_waitcnt vmcnt(4)" ::: "memory");  // tile0 landed
    __builtin_amdgcn_s_barrier();

    for (int t = 0; t < NT; ++t) {
        const int bb = t & 1;
        const u16* Ab = &As[bb][0];
        const u16* Bb = &Bs[bb][0];
        u16* Acur = &As[bb][0];
        u16* Bcur = &Bs[bb][0];
        u16* Anx  = &As[bb ^ 1][0];
        u16* Bnx  = &Bs[bb ^ 1][0];
        half8 af[4][2], bf[4][2];

        // ---------------- phase 0 ----------------
#pragma unroll
        for (int m = 0; m < 4; ++m)
#pragma unroll
            for (int ks = 0; ks < 2; ++ks)
                af[m][ks] = *(const half8*)&Ab[aofK[ks] + m * 1024];
#pragma unroll
        for (int n = 0; n < 2; ++n)
#pragma unroll
            for (int ks = 0; ks < 2; ++ks)
                bf[n][ks] = *(const half8*)&Bb[bofK[ks] + n * 1024];
        if (t + 1 < NT) STAGE(A, K, m0, t + 1, Anx, 1);
        __builtin_amdgcn_s_barrier();
        asm volatile("s_waitcnt lgkmcnt(0)" ::: "memory");
        __builtin_amdgcn_s_setprio(1);
#pragma unroll
        for (int m = 0; m < 4; ++m)
#pragma unroll
            for (int n = 0; n < 2; ++n)
#pragma unroll
                for (int ks = 0; ks < 2; ++ks)
                    MFMA_(acc[m][n], af[m][ks], bf[n][ks]);
        __builtin_amdgcn_s_setprio(0);
        __builtin_amdgcn_s_barrier();

        // ---------------- phase 1 ----------------
#pragma unroll
        for (int n = 2; n < 4; ++n)
#pragma unroll
            for (int ks = 0; ks < 2; ++ks)
                bf[n][ks] = *(const half8*)&Bb[bofK[ks] + n * 1024];
        if (t + 1 < NT) STAGE(Bt, K, n0, t + 1, Bnx, 1);
        __builtin_amdgcn_s_barrier();
        asm volatile("s_waitcnt lgkmcnt(0)" ::: "memory");
        __builtin_amdgcn_s_setprio(1);
#pragma unroll
        for (int m = 0; m < 4; ++m)
#pragma unroll
            for (int n = 2; n < 4; ++n)
#pragma unroll
                for (int ks = 0; ks < 2; ++ks)
                    MFMA_(acc[m][n], af[m][ks], bf[n][ks]);
        __builtin_amdgcn_s_setprio(0);
        __builtin_amdgcn_s_barrier();

        // ---------------- phase 2 ----------------
#pragma unroll
        for (int m = 0; m < 4; ++m)
#pragma unroll
            for (int ks = 0; ks < 2; ++ks)
                af[m][ks] = *(const half8*)&Ab[aofK[ks] + 4096 + m * 1024];
        if (t + 2 < NT) STAGE(Bt, K, n0, t + 2, Bcur, 0);
        __builtin_amdgcn_s_barrier();
        asm volatile("s_waitcnt lgkmcnt(0)" ::: "memory");
        __builtin_amdgcn_s_setprio(1);
#pragma unroll
        for (int m = 0; m < 4; ++m)
#pragma unroll
            for (int n = 0; n < 2; ++n)
#pragma unroll
                for (int ks = 0; ks < 2; ++ks)
                    MFMA_(acc[4 + m][n], af[m][ks], bf[n][ks]);
        __builtin_amdgcn_s_setprio(0);
        __builtin_amdgcn_s_barrier();

        // ---------------- phase 3 ----------------
        if (t + 2 < NT) STAGE(A, K, m0, t + 2, Acur, 0);
        __builtin_amdgcn_s_barrier();
        __builtin_amdgcn_s_setprio(1);
#pragma unroll
        for (int m = 0; m < 4; ++m)
#pragma unroll
            for (int n = 2; n < 4; ++n)
#pragma unroll
                for (int ks = 0; ks < 2; ++ks)
                    MFMA_(acc[4 + m][n], af[m][ks], bf[n][ks]);
        __builtin_amdgcn_s_setprio(0);
        if (t + 2 < NT)
            asm volatile("s_waitcnt vmcnt(4)" ::: "memory");
        else
            asm volatile("s_waitcnt vmcnt(0)" ::: "memory");
        __builtin_amdgcn_s_barrier();
    }

    // epilogue: C/D layout col = lane&15, row = (lane>>4)*4 + reg  [m89/m91]
    const int colbase = n0 + wn * 64 + fr;
    float bj[4];
#pragma unroll
    for (int j = 0; j < 4; ++j) bj[j] = bias[colbase + j * 16];

    if (MODE == 0) {
#pragma unroll
        for (int i = 0; i < 8; ++i) {
            int rowb = m0 + wr * 128 + i * 16 + (lane >> 4) * 4;
#pragma unroll
            for (int r = 0; r < 4; ++r) {
                size_t ro = (size_t)(rowb + r) * N;
#pragma unroll
                for (int j = 0; j < 4; ++j)
                    C[ro + colbase + j * 16] = f2h_bits(acc[i][j][r] + bj[j]);
            }
        }
    } else if (MODE == 1) {
#pragma unroll
        for (int i = 0; i < 8; ++i) {
            int rowb = m0 + wr * 128 + i * 16 + (lane >> 4) * 4;
#pragma unroll
            for (int r = 0; r < 4; ++r) {
                size_t ro = (size_t)(rowb + r) * N;
                float s = 0.f;
#pragma unroll
                for (int j = 0; j < 4; ++j) {
                    float d = acc[i][j][r] + bj[j] - Xref[ro + colbase + j * 16];
                    s += d * d;
                }
                // reduce over the 16 lanes sharing this row (cols)
                s += __shfl_xor(s, 1, 64);
                s += __shfl_xor(s, 2, 64);
                s += __shfl_xor(s, 4, 64);
                s += __shfl_xor(s, 8, 64);
                if (fr == 0) atomicAdd(&Lacc[rowb + r], s);
            }
        }
    } else {  // MODE 2: write C=H2 and accumulate L3/L4 partials vs Hoth=H1
        float wj[4];
#pragma unroll
        for (int j = 0; j < 4; ++j) wj[j] = Wo[colbase + j * 16];
#pragma unroll
        for (int i = 0; i < 8; ++i) {
            int rowb = m0 + wr * 128 + i * 16 + (lane >> 4) * 4;
#pragma unroll
            for (int r = 0; r < 4; ++r) {
                size_t ro = (size_t)(rowb + r) * N;
                float s3 = 0.f, s4 = 0.f;
#pragma unroll
                for (int j = 0; j < 4; ++j) {
                    float h2 = acc[i][j][r] + bj[j];
                    C[ro + colbase + j * 16] = f2h_bits(h2);
                    float h1 = h2f_bits(Hoth[ro + colbase + j * 16]);
                    float d = h1 - h2;
                    s3 += d * d;
                    s4 += (h1 + h2) * wj[j];
                }
                s3 += __shfl_xor(s3, 1, 64);
                s3 += __shfl_xor(s3, 2, 64);
                s3 += __shfl_xor(s3, 4, 64);
                s3 += __shfl_xor(s3, 8, 64);
                s4 += __shfl_xor(s4, 1, 64);
                s4 += __shfl_xor(s4, 2, 64);
                s4 += __shfl_xor(s4, 4, 64);
                s4 += __shfl_xor(s4, 8, 64);
                if (fr == 0) {
                    atomicAdd(&Lacc[rowb + r], s3);
                    atomicAdd(&L4o[rowb + r], s4);
                }
            }
        }
    }
#undef STAGE
#undef MFMA_
}

// ---------------------------------------------------------------------------
// loss = sum_r L1^2 + L2^2 + L3^2 + (0.5*(L4row + who_b) - Y)^2
__global__ __launch_bounds__(1024) void final_reduce(
    const float* __restrict__ L1, const float* __restrict__ L2,
    const float* __restrict__ L3, const float* __restrict__ L4,
    const float* __restrict__ Y, const float* __restrict__ whob,
    float* __restrict__ out) {
    float s = 0.f;
    float wb = whob[0];
    for (int r = threadIdx.x; r < NR; r += 1024) {
        float l4 = 0.5f * (L4[r] + wb) - Y[r];
        s += L1[r] * L1[r] + L2[r] * L2[r] + L3[r] * L3[r] + l4 * l4;
    }
#pragma unroll
    for (int off = 1; off < 64; off <<= 1) s += __shfl_xor(s, off, 64);
    __shared__ float sm[16];
    int w = threadIdx.x >> 6, ln = threadIdx.x & 63;
    if (ln == 0) sm[w] = s;
    __syncthreads();
    if (threadIdx.x == 0) {
        float t = 0.f;
#pragma unroll
        for (int i = 0; i < 16; ++i) t += sm[i];
        out[0] = t;
    }
}

// ---------------------------------------------------------------------------
extern "C" void kernel_launch(void* const* d_in, const int* in_sizes, int n_in,
                              void* d_out, int out_size, void* d_ws, size_t ws_size,
                              hipStream_t stream) {
    const float* X1   = (const float*)d_in[0];
    const float* X2   = (const float*)d_in[1];
    const float* Y    = (const float*)d_in[2];
    const float* w1hW = (const float*)d_in[3];
    const float* w1hb = (const float*)d_in[4];
    const float* w2hW = (const float*)d_in[5];
    const float* w2hb = (const float*)d_in[6];
    const float* wh1W = (const float*)d_in[7];
    const float* wh1b = (const float*)d_in[8];
    const float* wh2W = (const float*)d_in[9];
    const float* wh2b = (const float*)d_in[10];
    const float* whoW = (const float*)d_in[11];
    const float* whob = (const float*)d_in[12];

    // workspace layout (~208.3 MB total)
    char* ws = (char*)d_ws;
    u16* X1h  = (u16*)(ws);                               // 16384x1024 fp16
    u16* X2h  = X1h + (size_t)NR * DX;
    u16* H1h  = X2h + (size_t)NR * DX;                    // 16384x2048 fp16
    u16* H2h  = H1h + (size_t)NR * DH;
    u16* w1hT = H2h + (size_t)NR * DH;                    // [DH][DX]
    u16* w2hT = w1hT + (size_t)DH * DX;
    u16* wh1T = w2hT + (size_t)DH * DX;                   // [DX][DH]
    u16* wh2T = wh1T + (size_t)DX * DH;
    float* L1a = (float*)(wh2T + (size_t)DX * DH);        // 4 x 16384 f32
    float* L2a = L1a + NR;
    float* L3a = L2a + NR;
    float* L4a = L3a + NR;

    // zero all four atomically-accumulated arrays (ws poisoned 0xAA each call)
    hipMemsetAsync(L1a, 0, 4 * (size_t)NR * sizeof(float), stream);

    // casts
    cast_f32_f16<<<NR * DX / 1024, 256, 0, stream>>>(X1, X1h);
    cast_f32_f16<<<NR * DX / 1024, 256, 0, stream>>>(X2, X2h);
    transpose_cast<<<dim3(DH / 32, DX / 32), 256, 0, stream>>>(w1hW, w1hT, DX, DH);
    transpose_cast<<<dim3(DH / 32, DX / 32), 256, 0, stream>>>(w2hW, w2hT, DX, DH);
    transpose_cast<<<dim3(DX / 32, DH / 32), 256, 0, stream>>>(wh1W, wh1T, DH, DX);
    transpose_cast<<<dim3(DX / 32, DH / 32), 256, 0, stream>>>(wh2W, wh2T, DH, DX);

    // H1 = X1@w1h + b (MODE 0); H2 = X2@w2h + b fused with L3/L4 (MODE 2)
    gemm256<0><<<dim3((NR / 256) * (DH / 256)), 512, 0, stream>>>(
        X1h, w1hT, w1hb, H1h, nullptr, nullptr, nullptr, nullptr, nullptr,
        NR, DH, DX);
    gemm256<2><<<dim3((NR / 256) * (DH / 256)), 512, 0, stream>>>(
        X2h, w2hT, w2hb, H2h, nullptr, L3a, H1h, whoW, L4a,
        NR, DH, DX);

    // L1 = rowsq(H1@wh2 + b - X2), L2 = rowsq(H2@wh1 + b - X1)
    gemm256<1><<<dim3((NR / 256) * (DX / 256)), 512, 0, stream>>>(
        H1h, wh2T, wh2b, nullptr, X2, L1a, nullptr, nullptr, nullptr,
        NR, DX, DH);
    gemm256<1><<<dim3((NR / 256) * (DX / 256)), 512, 0, stream>>>(
        H2h, wh1T, wh1b, nullptr, X1, L2a, nullptr, nullptr, nullptr,
        NR, DX, DH);

    final_reduce<<<1, 1024, 0, stream>>>(L1a, L2a, L3a, L4a, Y, whob, (float*)d_out);
}

// Round 3
// 528.566 us; speedup vs baseline: 1.3218x; 1.0574x over previous
//
#include <hip/hip_runtime.h>
#include <cstdint>
#include <cstddef>

// Problem constants (reference: N=16384, DX1=DX2=1024, DH=2048)
#define NR 16384
#define DX 1024
#define DH 2048

typedef unsigned short u16;
typedef _Float16 half8 __attribute__((ext_vector_type(8)));
typedef _Float16 half4v __attribute__((ext_vector_type(4)));
typedef float f32x4 __attribute__((ext_vector_type(4)));

__device__ __forceinline__ u16 f2h_bits(float v) {
    union { _Float16 h; u16 u; } c;
    c.h = (_Float16)v;
    return c.u;
}

// async global->LDS, 16B per lane; LDS dest = wave-uniform base + lane*16
__device__ __forceinline__ void gl_lds16(const void* g, void* l) {
    __builtin_amdgcn_global_load_lds(
        (const __attribute__((address_space(1))) void*)g,
        (__attribute__((address_space(3))) void*)l, 16, 0, 0);
}

// ---------------------------------------------------------------------------
// fp32 -> fp16 elementwise cast (vectorized float4 -> half4). n must be %1024.
__global__ __launch_bounds__(256) void cast_f32_f16(const float* __restrict__ in,
                                                    u16* __restrict__ out) {
    size_t i = ((size_t)blockIdx.x * 256 + threadIdx.x) * 4;
    float4 v = *(const float4*)&in[i];
    half4v o = { (_Float16)v.x, (_Float16)v.y, (_Float16)v.z, (_Float16)v.w };
    *(half4v*)&out[i] = o;
}

// ---------------------------------------------------------------------------
// W [K,D] fp32 -> Wt [D,K] fp16 (LDS tiled transpose). K,D % 32 == 0.
__global__ __launch_bounds__(256) void transpose_cast(const float* __restrict__ in,
                                                      u16* __restrict__ out,
                                                      int K, int D) {
    __shared__ float tile[32][33];
    int tx = threadIdx.x & 31;
    int ty = threadIdx.x >> 5;                  // 0..7
    int d0 = blockIdx.x * 32, k0 = blockIdx.y * 32;
#pragma unroll
    for (int i = 0; i < 32; i += 8)
        tile[ty + i][tx] = in[(size_t)(k0 + ty + i) * D + d0 + tx];
    __syncthreads();
#pragma unroll
    for (int i = 0; i < 32; i += 8)
        out[(size_t)(d0 + ty + i) * K + k0 + tx] = f2h_bits(tile[tx][ty + i]);
}

// ---------------------------------------------------------------------------
// 256x256-tile 8-phase GEMM (m201 template, plain HIP), BK=64, 512 threads =
// 8 waves (2M x 4N), 16x16x32 f16 MFMA. A [M,K] f16 rm, Bt [N,K] f16 rm.
// LDS: As/Bs double-buffered [2][256][64] halfs = 128 KiB total -> 1 block/CU.
//
// Swizzle (T2, full 3-bit, derived for 128B rows + ds_read_b128):
//   LDS chunk (16B) at (row, c) holds global chunk (row, c ^ (row&7)).
//   Staged via pre-swizzled GLOBAL source chunk (rule #21, LDS dest linear);
//   ds_read XORs its half-offset with ((fr&7)<<3). Verified r2: conflicts=0.
//
// Phase schedule per K-tile t (buffer bb = t&1), WAR/RAW-safe:
//   p0: read a[0..3],b[0..1] | stage Ahi(t+1) | MFMA m0-3 x n0-1
//   p1: read b[2..3]         | stage Bhi(t+1) | MFMA m0-3 x n2-3
//   p2: read a[4..7]         | stage Blo(t+2) | MFMA m4-7 x n0-1
//   p3: (no reads)           | stage Alo(t+2) | MFMA m4-7 x n2-3, vmcnt(4|0)
//
// Epilogue (new r3): in-wave LDS repack so every lane owns 8 CONSECUTIVE
// cols of one row -> 16B half8 C-stores, float4 Xref/Wo loads, half8 Hoth
// loads (was 2B/lane scatter). Per-wave private f32 scratch overlaid on As
// (dead after K-loop), row stride 68 floats (16B aligned, <=2-way banks).
// Same-wave ds write->read ordering handled by compiler lgkmcnt (no barrier).
//
// MODE 0: C = A@B + bias (f16 out)
// MODE 1: Lacc[row] += sum_col (A@B + bias - Xref)^2          (atomic)
// MODE 2: C = A@B + bias (f16 out)  AND per-row L3/L4 partials vs Hoth:
//         Lacc[row] += sum_col (hoth - c)^2
//         L4o[row]  += sum_col (hoth + c) * Wo[col]           (atomic)
template <int MODE>
__global__ __launch_bounds__(512, 2) void gemm256(
    const u16* __restrict__ A, const u16* __restrict__ Bt,
    const float* __restrict__ bias,
    u16* __restrict__ C, const float* __restrict__ Xref,
    float* __restrict__ Lacc,
    const u16* __restrict__ Hoth, const float* __restrict__ Wo,
    float* __restrict__ L4o,
    int M, int N, int K) {
    __shared__ __align__(16) u16 As[2][16384];
    __shared__ __align__(16) u16 Bs[2][16384];

    // bijective XCD-aware block swizzle (nwg % 8 == 0 for all our shapes)
    const int nwg = gridDim.x;
    const int bid = blockIdx.x;
    const int cpx = nwg >> 3;
    const int wg  = (bid & 7) * cpx + (bid >> 3);
    const int NBN = N >> 8;
    const int m0 = (wg / NBN) * 256;
    const int n0 = (wg % NBN) * 256;

    const int tid  = threadIdx.x;
    const int lane = tid & 63;
    const int w    = tid >> 6;          // 0..7
    const int wr   = w >> 2;            // 0..1 (rows, 128 each)
    const int wn   = w & 3;             // 0..3 (cols, 64 each)
    const int fr   = lane & 15;
    const int qa   = (lane >> 4) * 8;   // k-offset (halfs) of lane's fragment
    const int NT   = K >> 6;            // K-tiles (>= 16 for our shapes)

    f32x4 acc[8][4] = {};

    // swizzled ds_read bases per ks (u16 units); qa+ks*32 folded pre-XOR.
    const int sx = (fr & 7) << 3;
    int aofK[2], bofK[2];
#pragma unroll
    for (int ks = 0; ks < 2; ++ks) {
        aofK[ks] = (((wr * 128 + fr) * 64) + qa + ks * 32) ^ sx;
        bofK[ks] = (((wn * 64 + fr) * 64) + qa + ks * 32) ^ sx;
    }

    // staging: one 128x64-half half-tile (16 KB) per call, two 8 KB sweeps.
    // source chunk pre-swizzled: cc_src = cc ^ (row & 7), row = tid>>3.
    const int stg_c = ((tid & 7) ^ ((tid >> 3) & 7)) << 3;           // halfs
    const int stg_r = tid >> 3;                                      // 0..63
    const int stg_w = (tid >> 6) << 9;  // wave-uniform LDS offset (halfs)

#define STAGE(G, ldK, rowbase, kt, lbase, half_idx)                            \
    do {                                                                       \
        const u16* _s = (G) + (size_t)((rowbase) + (half_idx) * 128 + stg_r) * \
                                  (ldK) + (kt) * 64 + stg_c;                   \
        u16* _d = (lbase) + (half_idx) * 8192 + stg_w;                         \
        gl_lds16(_s, _d);                                                      \
        gl_lds16(_s + (size_t)64 * (ldK), _d + 4096);                          \
    } while (0)

#define MFMA_(d, av, bv) \
    d = __builtin_amdgcn_mfma_f32_16x16x32_f16(av, bv, d, 0, 0, 0)

    // ---- prologue: tile0 (all 4 halves), then Blo(1), Alo(1) ----
    STAGE(A, K, m0, 0, &As[0][0], 0);
    STAGE(Bt, K, n0, 0, &Bs[0][0], 0);
    STAGE(A, K, m0, 0, &As[0][0], 1);
    STAGE(Bt, K, n0, 0, &Bs[0][0], 1);
    STAGE(Bt, K, n0, 1, &Bs[1][0], 0);
    STAGE(A, K, m0, 1, &As[1][0], 0);
    asm volatile("s_waitcnt vmcnt(4)" ::: "memory");  // tile0 landed
    __builtin_amdgcn_s_barrier();

    for (int t = 0; t < NT; ++t) {
        const int bb = t & 1;
        const u16* Ab = &As[bb][0];
        const u16* Bb = &Bs[bb][0];
        u16* Acur = &As[bb][0];
        u16* Bcur = &Bs[bb][0];
        u16* Anx  = &As[bb ^ 1][0];
        u16* Bnx  = &Bs[bb ^ 1][0];
        half8 af[4][2], bf[4][2];

        // ---------------- phase 0 ----------------
#pragma unroll
        for (int m = 0; m < 4; ++m)
#pragma unroll
            for (int ks = 0; ks < 2; ++ks)
                af[m][ks] = *(const half8*)&Ab[aofK[ks] + m * 1024];
#pragma unroll
        for (int n = 0; n < 2; ++n)
#pragma unroll
            for (int ks = 0; ks < 2; ++ks)
                bf[n][ks] = *(const half8*)&Bb[bofK[ks] + n * 1024];
        if (t + 1 < NT) STAGE(A, K, m0, t + 1, Anx, 1);
        __builtin_amdgcn_s_barrier();
        asm volatile("s_waitcnt lgkmcnt(0)" ::: "memory");
        __builtin_amdgcn_s_setprio(1);
#pragma unroll
        for (int m = 0; m < 4; ++m)
#pragma unroll
            for (int n = 0; n < 2; ++n)
#pragma unroll
                for (int ks = 0; ks < 2; ++ks)
                    MFMA_(acc[m][n], af[m][ks], bf[n][ks]);
        __builtin_amdgcn_s_setprio(0);
        __builtin_amdgcn_s_barrier();

        // ---------------- phase 1 ----------------
#pragma unroll
        for (int n = 2; n < 4; ++n)
#pragma unroll
            for (int ks = 0; ks < 2; ++ks)
                bf[n][ks] = *(const half8*)&Bb[bofK[ks] + n * 1024];
        if (t + 1 < NT) STAGE(Bt, K, n0, t + 1, Bnx, 1);
        __builtin_amdgcn_s_barrier();
        asm volatile("s_waitcnt lgkmcnt(0)" ::: "memory");
        __builtin_amdgcn_s_setprio(1);
#pragma unroll
        for (int m = 0; m < 4; ++m)
#pragma unroll
            for (int n = 2; n < 4; ++n)
#pragma unroll
                for (int ks = 0; ks < 2; ++ks)
                    MFMA_(acc[m][n], af[m][ks], bf[n][ks]);
        __builtin_amdgcn_s_setprio(0);
        __builtin_amdgcn_s_barrier();

        // ---------------- phase 2 ----------------
#pragma unroll
        for (int m = 0; m < 4; ++m)
#pragma unroll
            for (int ks = 0; ks < 2; ++ks)
                af[m][ks] = *(const half8*)&Ab[aofK[ks] + 4096 + m * 1024];
        if (t + 2 < NT) STAGE(Bt, K, n0, t + 2, Bcur, 0);
        __builtin_amdgcn_s_barrier();
        asm volatile("s_waitcnt lgkmcnt(0)" ::: "memory");
        __builtin_amdgcn_s_setprio(1);
#pragma unroll
        for (int m = 0; m < 4; ++m)
#pragma unroll
            for (int n = 0; n < 2; ++n)
#pragma unroll
                for (int ks = 0; ks < 2; ++ks)
                    MFMA_(acc[4 + m][n], af[m][ks], bf[n][ks]);
        __builtin_amdgcn_s_setprio(0);
        __builtin_amdgcn_s_barrier();

        // ---------------- phase 3 ----------------
        if (t + 2 < NT) STAGE(A, K, m0, t + 2, Acur, 0);
        __builtin_amdgcn_s_barrier();
        __builtin_amdgcn_s_setprio(1);
#pragma unroll
        for (int m = 0; m < 4; ++m)
#pragma unroll
            for (int n = 2; n < 4; ++n)
#pragma unroll
                for (int ks = 0; ks < 2; ++ks)
                    MFMA_(acc[4 + m][n], af[m][ks], bf[n][ks]);
        __builtin_amdgcn_s_setprio(0);
        if (t + 2 < NT)
            asm volatile("s_waitcnt vmcnt(4)" ::: "memory");
        else
            asm volatile("s_waitcnt vmcnt(0)" ::: "memory");
        __builtin_amdgcn_s_barrier();
    }

    // ---- epilogue: in-wave LDS repack -> coalesced 16B accesses ----
    // C/D layout: col = lane&15 (+j*16), row = (lane>>4)*4 + reg  [m89/m91]
    // Per-wave private scratch (16 rows x 64 cols f32, row stride 68).
    float* scratch = (float*)&As[0][0] + (size_t)w * 1088;  // 4352B/wave
    const int q  = lane >> 4;        // quarter-group = row block
    const int sr = lane >> 3;        // read-phase subrow 0..7
    const int cc = (lane & 7) * 8;   // read-phase col chunk

    const int colbase = n0 + wn * 64 + fr;
    float bj[4];
#pragma unroll
    for (int j = 0; j < 4; ++j) bj[j] = bias[colbase + j * 16];

#pragma unroll
    for (int i = 0; i < 8; ++i) {
        // write phase: scatter acc+bias into scratch rows 0..15
#pragma unroll
        for (int j = 0; j < 4; ++j)
#pragma unroll
            for (int r = 0; r < 4; ++r)
                scratch[(q * 4 + r) * 68 + fr + j * 16] = acc[i][j][r] + bj[j];
        // read phase: two sub-passes of 8 rows; lane owns 8 consecutive cols
#pragma unroll
        for (int h = 0; h < 2; ++h) {
            const int r16 = h * 8 + sr;
            const float* src = &scratch[r16 * 68 + cc];
            float v[8];
            *(f32x4*)&v[0] = *(const f32x4*)&src[0];
            *(f32x4*)&v[4] = *(const f32x4*)&src[4];
            const int rowg = m0 + wr * 128 + i * 16 + r16;
            const int colg = n0 + wn * 64 + cc;
            const size_t off = (size_t)rowg * N + colg;

            if (MODE == 0 || MODE == 2) {
                half8 hv;
#pragma unroll
                for (int u = 0; u < 8; ++u) hv[u] = (_Float16)v[u];
                *(half8*)&C[off] = hv;
            }
            if (MODE == 1) {
                float4 x0 = *(const float4*)&Xref[off];
                float4 x1 = *(const float4*)&Xref[off + 4];
                float xr[8] = { x0.x, x0.y, x0.z, x0.w, x1.x, x1.y, x1.z, x1.w };
                float s = 0.f;
#pragma unroll
                for (int u = 0; u < 8; ++u) {
                    float d = v[u] - xr[u];
                    s += d * d;
                }
                s += __shfl_xor(s, 1, 64);
                s += __shfl_xor(s, 2, 64);
                s += __shfl_xor(s, 4, 64);
                if ((lane & 7) == 0) atomicAdd(&Lacc[rowg], s);
            }
            if (MODE == 2) {
                half8 hh = *(const half8*)&Hoth[off];
                float4 w0 = *(const float4*)&Wo[colg];
                float4 w1 = *(const float4*)&Wo[colg + 4];
                float wv[8] = { w0.x, w0.y, w0.z, w0.w, w1.x, w1.y, w1.z, w1.w };
                float s3 = 0.f, s4 = 0.f;
#pragma unroll
                for (int u = 0; u < 8; ++u) {
                    float h1 = (float)hh[u];
                    float d = h1 - v[u];
                    s3 += d * d;
                    s4 += (h1 + v[u]) * wv[u];
                }
                s3 += __shfl_xor(s3, 1, 64);
                s3 += __shfl_xor(s3, 2, 64);
                s3 += __shfl_xor(s3, 4, 64);
                s4 += __shfl_xor(s4, 1, 64);
                s4 += __shfl_xor(s4, 2, 64);
                s4 += __shfl_xor(s4, 4, 64);
                if ((lane & 7) == 0) {
                    atomicAdd(&Lacc[rowg], s3);
                    atomicAdd(&L4o[rowg], s4);
                }
            }
        }
    }
#undef STAGE
#undef MFMA_
}

// ---------------------------------------------------------------------------
// loss = sum_r L1^2 + L2^2 + L3^2 + (0.5*(L4row + who_b) - Y)^2
// grid = NR/256 blocks, one row per thread, atomicAdd into pre-zeroed out[0].
__global__ __launch_bounds__(256) void final_reduce(
    const float* __restrict__ L1, const float* __restrict__ L2,
    const float* __restrict__ L3, const float* __restrict__ L4,
    const float* __restrict__ Y, const float* __restrict__ whob,
    float* __restrict__ out) {
    int r = blockIdx.x * 256 + threadIdx.x;
    float wb = whob[0];
    float l4 = 0.5f * (L4[r] + wb) - Y[r];
    float s = L1[r] * L1[r] + L2[r] * L2[r] + L3[r] * L3[r] + l4 * l4;
#pragma unroll
    for (int off = 1; off < 64; off <<= 1) s += __shfl_xor(s, off, 64);
    __shared__ float sm[4];
    int w = threadIdx.x >> 6, ln = threadIdx.x & 63;
    if (ln == 0) sm[w] = s;
    __syncthreads();
    if (threadIdx.x == 0)
        atomicAdd(out, sm[0] + sm[1] + sm[2] + sm[3]);
}

// ---------------------------------------------------------------------------
extern "C" void kernel_launch(void* const* d_in, const int* in_sizes, int n_in,
                              void* d_out, int out_size, void* d_ws, size_t ws_size,
                              hipStream_t stream) {
    const float* X1   = (const float*)d_in[0];
    const float* X2   = (const float*)d_in[1];
    const float* Y    = (const float*)d_in[2];
    const float* w1hW = (const float*)d_in[3];
    const float* w1hb = (const float*)d_in[4];
    const float* w2hW = (const float*)d_in[5];
    const float* w2hb = (const float*)d_in[6];
    const float* wh1W = (const float*)d_in[7];
    const float* wh1b = (const float*)d_in[8];
    const float* wh2W = (const float*)d_in[9];
    const float* wh2b = (const float*)d_in[10];
    const float* whoW = (const float*)d_in[11];
    const float* whob = (const float*)d_in[12];

    // workspace layout (~208.3 MB total)
    char* ws = (char*)d_ws;
    u16* X1h  = (u16*)(ws);                               // 16384x1024 fp16
    u16* X2h  = X1h + (size_t)NR * DX;
    u16* H1h  = X2h + (size_t)NR * DX;                    // 16384x2048 fp16
    u16* H2h  = H1h + (size_t)NR * DH;
    u16* w1hT = H2h + (size_t)NR * DH;                    // [DH][DX]
    u16* w2hT = w1hT + (size_t)DH * DX;
    u16* wh1T = w2hT + (size_t)DH * DX;                   // [DX][DH]
    u16* wh2T = wh1T + (size_t)DX * DH;
    float* L1a = (float*)(wh2T + (size_t)DX * DH);        // 4 x 16384 f32
    float* L2a = L1a + NR;
    float* L3a = L2a + NR;
    float* L4a = L3a + NR;

    // zero atomically-accumulated arrays + output (ws poisoned 0xAA each call)
    hipMemsetAsync(L1a, 0, 4 * (size_t)NR * sizeof(float), stream);
    hipMemsetAsync(d_out, 0, sizeof(float), stream);

    // casts
    cast_f32_f16<<<NR * DX / 1024, 256, 0, stream>>>(X1, X1h);
    cast_f32_f16<<<NR * DX / 1024, 256, 0, stream>>>(X2, X2h);
    transpose_cast<<<dim3(DH / 32, DX / 32), 256, 0, stream>>>(w1hW, w1hT, DX, DH);
    transpose_cast<<<dim3(DH / 32, DX / 32), 256, 0, stream>>>(w2hW, w2hT, DX, DH);
    transpose_cast<<<dim3(DX / 32, DH / 32), 256, 0, stream>>>(wh1W, wh1T, DH, DX);
    transpose_cast<<<dim3(DX / 32, DH / 32), 256, 0, stream>>>(wh2W, wh2T, DH, DX);

    // H1 = X1@w1h + b (MODE 0); H2 = X2@w2h + b fused with L3/L4 (MODE 2)
    gemm256<0><<<dim3((NR / 256) * (DH / 256)), 512, 0, stream>>>(
        X1h, w1hT, w1hb, H1h, nullptr, nullptr, nullptr, nullptr, nullptr,
        NR, DH, DX);
    gemm256<2><<<dim3((NR / 256) * (DH / 256)), 512, 0, stream>>>(
        X2h, w2hT, w2hb, H2h, nullptr, L3a, H1h, whoW, L4a,
        NR, DH, DX);

    // L1 = rowsq(H1@wh2 + b - X2), L2 = rowsq(H2@wh1 + b - X1)
    gemm256<1><<<dim3((NR / 256) * (DX / 256)), 512, 0, stream>>>(
        H1h, wh2T, wh2b, nullptr, X2, L1a, nullptr, nullptr, nullptr,
        NR, DX, DH);
    gemm256<1><<<dim3((NR / 256) * (DX / 256)), 512, 0, stream>>>(
        H2h, wh1T, wh1b, nullptr, X1, L2a, nullptr, nullptr, nullptr,
        NR, DX, DH);

    final_reduce<<<NR / 256, 256, 0, stream>>>(L1a, L2a, L3a, L4a, Y, whob,
                                               (float*)d_out);
}